// Round 1
// baseline (228.356 us; speedup 1.0000x reference)
//
#include <hip/hip_runtime.h>
#include <math.h>

#define NB 16
#define NC 48
#define NT 96
#define NP 12
#define NFF 64
#define CT 4608          // NC*NT
#define STEPS 7

// ---- exact-GELU via Abramowitz-Stegun 7.1.26 erf (|abs err| <= 1.5e-7) ----
__device__ __forceinline__ float erf_fast(float x) {
    float a = fabsf(x);
    float t = __builtin_amdgcn_rcpf(fmaf(0.3275911f, a, 1.0f));
    float p = t * fmaf(t, fmaf(t, fmaf(t, fmaf(t, 1.061405429f, -1.453152027f),
                                       1.421413741f), -0.284496736f), 0.254829592f);
    float E = __builtin_amdgcn_exp2f(-a * a * 1.4426950408889634f);
    float y = fmaf(-p, E, 1.0f);
    return copysignf(y, x);
}
__device__ __forceinline__ float gelu_exact(float u) {
    float e  = erf_fast(u * 0.70710678118654752f);
    float hu = 0.5f * u;
    return fmaf(hu, e, hu);
}

// ---- kernel 0: BN over full x; writes xn (ws) and first patch into d_out ----
__global__ __launch_bounds__(256) void bn0_kernel(
    const float* __restrict__ x, const float* __restrict__ g0,
    const float* __restrict__ b0, float* __restrict__ xn, float* __restrict__ out)
{
    int f = blockIdx.x * blockDim.x + threadIdx.x;   // feature = c*96 + tt
    if (f >= CT) return;
    float v[NB];
    float s = 0.f;
#pragma unroll
    for (int b = 0; b < NB; b++) { v[b] = x[b * CT + f]; s += v[b]; }
    float mu = s * (1.f / NB);
    float var = 0.f;
#pragma unroll
    for (int b = 0; b < NB; b++) { float d = v[b] - mu; var = fmaf(d, d, var); }
    var *= (1.f / NB);
    float rs = rsqrtf(var + 1e-5f);
    float g = g0[f], bb = b0[f];
    int c = f / NT, tt = f % NT;
#pragma unroll
    for (int b = 0; b < NB; b++) {
        float y = (v[b] - mu) * rs * g + bb;
        xn[b * CT + f] = y;
        if (tt < NP) out[(b * NC + c) * NT + tt] = y;   // 'first' slice
    }
}

// ---- per-step phase 1: BN1 -> agg matmul + gelu -> +xw -> BN2 -> t ----
// one block per channel c; 192 threads = (b,p)
__global__ __launch_bounds__(192) void phase1_kernel(
    const float* __restrict__ prev_base,  // = d_out; prev slice at col 12*s
    const float* __restrict__ xn,
    const float* __restrict__ g1, const float* __restrict__ b1,
    const float* __restrict__ g2, const float* __restrict__ b2,
    const float* __restrict__ Wagg, const float* __restrict__ bagg,
    float* __restrict__ res_ws, float* __restrict__ t_ws, int s)
{
    int c = blockIdx.x;
    int tid = threadIdx.x;
    int b = tid / NP, p = tid % NP;
    __shared__ float sh[192], shB[192], wagg[144];
    if (tid < 144) wagg[tid] = Wagg[tid];
    float v = prev_base[(b * NC + c) * NT + NP * s + p];
    sh[tid] = v;
    __syncthreads();
    // BN1 over b (feature = c*12+p)
    float s1 = 0.f;
#pragma unroll
    for (int bb2 = 0; bb2 < NB; bb2++) s1 += sh[bb2 * NP + p];
    float mu = s1 * (1.f / NB);
    float var = 0.f;
#pragma unroll
    for (int bb2 = 0; bb2 < NB; bb2++) { float d = sh[bb2 * NP + p] - mu; var = fmaf(d, d, var); }
    var *= (1.f / NB);
    float inp = (v - mu) * rsqrtf(var + 1e-5f) * g1[c * NP + p] + b1[c * NP + p];
    shB[tid] = inp;
    __syncthreads();
    // agg matmul over p (q = this thread's p), gelu, add xw
    float acc = bagg[p];
#pragma unroll
    for (int pp = 0; pp < NP; pp++) acc = fmaf(shB[b * NP + pp], wagg[p * NP + pp], acc);
    float res = gelu_exact(acc) + xn[(b * NC + c) * NT + NP + NP * s + p];
    res_ws[(b * NC + c) * NP + p] = res;
    sh[tid] = res;
    __syncthreads();
    // BN2 over b
    float s2 = 0.f;
#pragma unroll
    for (int bb2 = 0; bb2 < NB; bb2++) s2 += sh[bb2 * NP + p];
    float mu2 = s2 * (1.f / NB);
    float var2 = 0.f;
#pragma unroll
    for (int bb2 = 0; bb2 < NB; bb2++) { float d = sh[bb2 * NP + p] - mu2; var2 = fmaf(d, d, var2); }
    var2 *= (1.f / NB);
    float t = (res - mu2) * rsqrtf(var2 + 1e-5f) * g2[c * NP + p] + b2[c * NP + p];
    t_ws[(b * NP + p) * NC + c] = t;   // t[b][p][c]
}

// ---- per-step edge MLP + top-3 + softmax + message + out ----
// grid: 9216 rows / 4 rows-per-block = 2304 blocks x 192 threads (lane = j)
__global__ __launch_bounds__(192) void edge_kernel(
    const float* __restrict__ t_ws, const float* __restrict__ res_ws,
    const float* __restrict__ W1, const float* __restrict__ bm1,
    const float* __restrict__ W2, const float* __restrict__ wmsg,
    const float* __restrict__ bmsg, float* __restrict__ out, int s)
{
    int tid = threadIdx.x;
    int row0 = blockIdx.x * 4;
    int bp = row0 / NC;            // same for whole block (4 | 48)
    int b = bp / NP, p = bp % NP;
    int i0 = row0 % NC;

    __shared__ float4 coef[NFF];
    __shared__ float tv[NC];
    __shared__ float erow[4][NC];
    __shared__ float red[4][2];    // [sum w, sum w*msg]

    if (tid < NFF) coef[tid] = make_float4(W1[2 * tid], W1[2 * tid + 1], bm1[tid], W2[tid]);
    if (tid < NC)  tv[tid] = t_ws[bp * NC + tid];
    if (tid < 8)   ((float*)red)[tid] = 0.f;
    __syncthreads();

    int rl = tid / NC, j = tid % NC;
    int i = i0 + rl;
    float zi = tv[i], zj = tv[j];

    float e = 0.f;
#pragma unroll 8
    for (int f = 0; f < NFF; f++) {
        float4 cf = coef[f];
        float u = fmaf(cf.x, zi, fmaf(cf.y, zj, cf.z));
        e = fmaf(gelu_exact(u), cf.w, e);
    }
    erow[rl][j] = e;
    __syncthreads();

    // rank (jax top_k tie-break: lower index first) + row max
    float mx = -1e30f;
    int rank = 0;
#pragma unroll 8
    for (int k = 0; k < NC; k++) {
        float ek = erow[rl][k];
        mx = fmaxf(mx, ek);
        rank += (ek > e) || (ek == e && k < j);
    }
    if (rank < 3) {
        float w = __builtin_amdgcn_exp2f((e - mx) * 1.4426950408889634f);
        float msg = fmaf(zj, wmsg[0], bmsg[0]);
        atomicAdd(&red[rl][0], w);
        atomicAdd(&red[rl][1], w * msg);
    }
    __syncthreads();

    if (j == 0) {
        float znew = red[rl][1] / red[rl][0];
        out[(b * NC + i) * NT + NP * (s + 1) + p] =
            res_ws[(b * NC + i) * NP + p] + 0.5f * znew;   // ALPHA = 0.5
    }
}

extern "C" void kernel_launch(void* const* d_in, const int* in_sizes, int n_in,
                              void* d_out, int out_size, void* d_ws, size_t ws_size,
                              hipStream_t stream)
{
    const float* x    = (const float*)d_in[0];
    const float* g0   = (const float*)d_in[1];
    const float* b0   = (const float*)d_in[2];
    const float* g1   = (const float*)d_in[3];
    const float* b1   = (const float*)d_in[4];
    const float* g2   = (const float*)d_in[5];
    const float* b2   = (const float*)d_in[6];
    const float* Wagg = (const float*)d_in[7];
    const float* bagg = (const float*)d_in[8];
    const float* W1   = (const float*)d_in[9];
    const float* bm1  = (const float*)d_in[10];
    const float* W2   = (const float*)d_in[11];
    // d_in[12] = bm2: uniform shift of e -> invariant under top-k & softmax; unused
    const float* wmsg = (const float*)d_in[13];
    const float* bmsg = (const float*)d_in[14];
    float* out = (float*)d_out;

    float* xn     = (float*)d_ws;          // 73728 floats
    float* t_ws   = xn + (NB * CT);        // 9216 floats
    float* res_ws = t_ws + (NB * NP * NC); // 9216 floats

    bn0_kernel<<<CT / 256, 256, 0, stream>>>(x, g0, b0, xn, out);
    for (int s = 0; s < STEPS; s++) {
        phase1_kernel<<<NC, 192, 0, stream>>>(out, xn, g1, b1, g2, b2, Wagg, bagg,
                                              res_ws, t_ws, s);
        edge_kernel<<<(NB * NP * NC) / 4, 192, 0, stream>>>(t_ws, res_ws, W1, bm1, W2,
                                                            wmsg, bmsg, out, s);
    }
}